// Round 18
// baseline (84.361 us; speedup 1.0000x reference)
//
#include <hip/hip_runtime.h>
#include <hip/hip_bf16.h>

typedef _Float16 half8 __attribute__((ext_vector_type(8)));
typedef float f32x4 __attribute__((ext_vector_type(4)));
typedef unsigned int u32x4 __attribute__((ext_vector_type(4)));

#define N_U      4096
#define N_L      65536
#define NZ       32
#define NSPLIT   256                  // L splits (grid.x of kA)
#define LSLICE   (N_L / NSPLIT)       // 256 L rows per block -> 16 tiles
#define NT       (LSLICE / 16)        // 16 L-tiles per block
#define UT       16                   // u-tiles per wave (16 MFMA per A-load)
#define BM       1024                 // U rows per kA block (4 waves x 16 x 16)
#define GY       (N_U / BM)           // 4
#define NBLK     (NSPLIT * GY)        // 1024 kA blocks
#define LDS_STRIDE 80                 // 64B f16 + 16B pad: bank base lc*20+g*4,
                                      // 5 coprime 32 -> uniform 2 lanes/bank

// workspace layout
#define OFF_P1   0                            // u32 P1key[N_U] (16 KB)
#define OFF_USQ  (16 * 1024)                  // float usq[N_U]  (16 KB)
#define OFF_CNT  (32 * 1024)                  // u32 done-counter
#define OFF_LF   (36 * 1024)                  // _Float16 Lf16[N_L][32] (4 MB)
#define OFF_LSQ  (OFF_LF + N_L * NZ * 2)      // float lsqh[N_L] = -0.5*||l||^2
#define OFF_UF   (OFF_LSQ + N_L * 4)          // _Float16 Uf16[N_U][32]

// Order-preserving float <-> uint key (monotone for all finite floats)
__device__ __forceinline__ unsigned int f2key(float f) {
    unsigned int u = __float_as_uint(f);
    return (u & 0x80000000u) ? ~u : (u | 0x80000000u);
}
__device__ __forceinline__ float key2f(unsigned int k) {
    unsigned int u = (k & 0x80000000u) ? (k & 0x7FFFFFFFu) : ~k;
    return __uint_as_float(u);
}

// ---------------------------------------------------------------------------
// Precompute: L -> f16 + (-0.5*||l||^2); U -> f16 + ||u||^2; init P1key+cnt.
__global__ __launch_bounds__(256) void kPre(const float* __restrict__ Uz,
                                            const float* __restrict__ Lz,
                                            _Float16* __restrict__ Lf16,
                                            float* __restrict__ lsqh,
                                            _Float16* __restrict__ Uf16,
                                            float* __restrict__ usq,
                                            unsigned int* __restrict__ P1key,
                                            unsigned int* __restrict__ cnt) {
    int r = blockIdx.x * 256 + threadIdx.x;
    if (r == 0) cnt[0] = 0u;
    if (r < N_L) {
        const f32x4* src = (const f32x4*)(Lz + (size_t)r * NZ);
        _Float16* dst = Lf16 + (size_t)r * NZ;
        float s = 0.f;
#pragma unroll
        for (int j = 0; j < 4; ++j) {
            f32x4 a = src[2 * j], b = src[2 * j + 1];
            s = fmaf(a[0], a[0], s); s = fmaf(a[1], a[1], s);
            s = fmaf(a[2], a[2], s); s = fmaf(a[3], a[3], s);
            s = fmaf(b[0], b[0], s); s = fmaf(b[1], b[1], s);
            s = fmaf(b[2], b[2], s); s = fmaf(b[3], b[3], s);
            *(half8*)(dst + j * 8) =
                (half8){(_Float16)a[0], (_Float16)a[1], (_Float16)a[2], (_Float16)a[3],
                        (_Float16)b[0], (_Float16)b[1], (_Float16)b[2], (_Float16)b[3]};
        }
        lsqh[r] = -0.5f * s;
    } else if (r < N_L + N_U) {
        int u = r - N_L;
        const f32x4* src = (const f32x4*)(Uz + (size_t)u * NZ);
        _Float16* dst = Uf16 + (size_t)u * NZ;
        float s = 0.f;
#pragma unroll
        for (int j = 0; j < 4; ++j) {
            f32x4 a = src[2 * j], b = src[2 * j + 1];
            s = fmaf(a[0], a[0], s); s = fmaf(a[1], a[1], s);
            s = fmaf(a[2], a[2], s); s = fmaf(a[3], a[3], s);
            s = fmaf(b[0], b[0], s); s = fmaf(b[1], b[1], s);
            s = fmaf(b[2], b[2], s); s = fmaf(b[3], b[3], s);
            *(half8*)(dst + j * 8) =
                (half8){(_Float16)a[0], (_Float16)a[1], (_Float16)a[2], (_Float16)a[3],
                        (_Float16)b[0], (_Float16)b[1], (_Float16)b[2], (_Float16)b[3]};
        }
        usq[u] = s;
        P1key[u] = 0u;   // key-space -inf
    }
}

// ---------------------------------------------------------------------------
// Heavy kernel (R17-proven: LDS-staged L-slice, stride-80 conflict-free,
// UT=16 pinned bfrag, wave stagger, waves_per_eu(4,4)) + FUSED FINISHER:
// last block (done-counter) computes dd + min/max + normalize inline,
// removing the kB launch + inter-kernel gap. P1key read back via
// atomicMax(p,0) -> device-scope-coherent old value.
__global__ __launch_bounds__(256)
__attribute__((amdgpu_waves_per_eu(4, 4)))
void kA(const _Float16* __restrict__ Lf16,
        const float* __restrict__ lsqh,
        const _Float16* __restrict__ Uf16,
        const float* __restrict__ usq,
        unsigned int* __restrict__ P1key,
        unsigned int* __restrict__ cnt,
        float* __restrict__ out) {
    __shared__ __align__(16) unsigned char sm[LSLICE * LDS_STRIDE + LSLICE * 4];
    __shared__ unsigned int lastflag;
    float* slsq = (float*)(sm + LSLICE * LDS_STRIDE);

    const int tid  = threadIdx.x;
    const int lane = tid & 63;
    const int wave = tid >> 6;
    const int g    = lane >> 4;    // k-chunk 0..3 (k = g*8+e, same perm A and B)
    const int lc   = lane & 15;

    const int ubase = blockIdx.y * BM + wave * (UT * 16);
    const int lbase = blockIdx.x * LSLICE;

    // ---- stage: thread t -> L row t (4 x 16B, coalesced global, 2-way LDS)
    {
        const half8* src = (const half8*)(Lf16 + (size_t)(lbase + tid) * NZ);
        unsigned char* dst = sm + tid * LDS_STRIDE;
#pragma unroll
        for (int j = 0; j < 4; ++j)
            *(half8*)(dst + j * 16) = src[j];
        slsq[tid] = lsqh[lbase + tid];
    }

    half8 bfrag[UT];
#pragma unroll
    for (int t = 0; t < UT; ++t)
        bfrag[t] = *(const half8*)(Uf16 + (size_t)(ubase + t * 16 + lc) * NZ + g * 8);
    // Pin B-fragments: opaque non-rematerializable defs (R13: kept resident).
#pragma unroll
    for (int t = 0; t < UT; ++t)
        asm volatile("" : "+v"(bfrag[t]));

    float m[UT];
#pragma unroll
    for (int t = 0; t < UT; ++t) m[t] = -INFINITY;

    __syncthreads();

    const unsigned char* abase = sm + lc * LDS_STRIDE + g * 16;

#pragma unroll 2
    for (int lt = 0; lt < NT; ++lt) {
        const int pt = (lt + wave * 4) & (NT - 1);   // per-wave phase stagger
        half8 a = *(const half8*)(abase + pt * (16 * LDS_STRIDE));
        f32x4 c = *(const f32x4*)(slsq + pt * 16 + g * 4);   // 16-lane broadcast
#pragma unroll
        for (int t = 0; t < UT; ++t) {
            f32x4 x = __builtin_amdgcn_mfma_f32_16x16x32_f16(a, bfrag[t], c, 0, 0, 0);
            float y = fmaxf(fmaxf(x[0], x[1]), x[2]);        // v_max3
            m[t] = fmaxf(fmaxf(y, x[3]), m[t]);              // v_max3
        }
    }

#pragma unroll
    for (int t = 0; t < UT; ++t) {
        float v = m[t];
        v = fmaxf(v, __shfl_xor(v, 16));
        v = fmaxf(v, __shfl_xor(v, 32));
        if (g == 0)
            atomicMax(&P1key[ubase + t * 16 + lc], f2key(v));
    }

    // ---- last-block fused finisher --------------------------------------
    __threadfence();                       // publishes visible before cnt inc
    __syncthreads();                       // all threads' fences done
    if (tid == 0)
        lastflag = (atomicAdd(cnt, 1u) == NBLK - 1) ? 1u : 0u;
    __syncthreads();
    if (lastflag) {
        float* red = (float*)sm;           // sm free after main loop
        float ddv[16], lmin = INFINITY, lmax = -INFINITY;
#pragma unroll
        for (int j = 0; j < 16; ++j) {
            int u = j * 256 + tid;
            unsigned int key = atomicMax(&P1key[u], 0u);   // coherent read
            float M    = key2f(key);                       // max(u.l - .5||l||^2)
            float s    = usq[u];
            float sq   = fmaxf(fmaf(-2.f, M, s), 0.f);     // min squared dist
            float dens = -0.5f * s - 29.406033062549525f;  // -.5||u||^2-16log2pi
            ddv[j] = expf(dens) * (sqrtf(sq) + 1e-18f);
            lmin = fminf(lmin, ddv[j]);
            lmax = fmaxf(lmax, ddv[j]);
        }
#pragma unroll
        for (int o = 1; o < 64; o <<= 1) {
            lmin = fminf(lmin, __shfl_xor(lmin, o));
            lmax = fmaxf(lmax, __shfl_xor(lmax, o));
        }
        if (lane == 0) { red[wave] = lmin; red[4 + wave] = lmax; }
        __syncthreads();
        float mn  = fminf(fminf(red[0], red[1]), fminf(red[2], red[3]));
        float mx  = fmaxf(fmaxf(red[4], red[5]), fmaxf(red[6], red[7]));
        float inv = 1.f / ((mx - mn) + 1e-18f);
#pragma unroll
        for (int j = 0; j < 16; ++j)
            out[j * 256 + tid] = (ddv[j] - mn) * inv;
    }
}

// ---------------------------------------------------------------------------
extern "C" void kernel_launch(void* const* d_in, const int* in_sizes, int n_in,
                              void* d_out, int out_size, void* d_ws, size_t ws_size,
                              hipStream_t stream) {
    const float* Uz = (const float*)d_in[1];
    const float* Lz = (const float*)d_in[2];
    float* out = (float*)d_out;
    unsigned char* ws = (unsigned char*)d_ws;

    unsigned int* P1key = (unsigned int*)(ws + OFF_P1);
    float*        usq   = (float*)(ws + OFF_USQ);
    unsigned int* cnt   = (unsigned int*)(ws + OFF_CNT);
    _Float16*     Lf16  = (_Float16*)(ws + OFF_LF);
    float*        lsqh  = (float*)(ws + OFF_LSQ);
    _Float16*     Uf16  = (_Float16*)(ws + OFF_UF);

    kPre<<<(N_L + N_U + 255) / 256, 256, 0, stream>>>(Uz, Lz, Lf16, lsqh, Uf16,
                                                      usq, P1key, cnt);
    dim3 grid(NSPLIT, GY);   // 256 x 4 = 1024 blocks = 4/CU, one full round
    kA<<<grid, 256, 0, stream>>>(Lf16, lsqh, Uf16, usq, P1key, cnt, out);
}

// Round 20
// 50.999 us; speedup vs baseline: 1.6542x; 1.6542x over previous
//
#include <hip/hip_runtime.h>
#include <hip/hip_bf16.h>

typedef _Float16 half8 __attribute__((ext_vector_type(8)));
typedef float f32x4 __attribute__((ext_vector_type(4)));
typedef unsigned int u32x4 __attribute__((ext_vector_type(4)));

#define N_U      4096
#define N_L      65536
#define NZ       32
#define NSPLIT   256                  // L splits (grid.x of kA)
#define LSLICE   (N_L / NSPLIT)       // 256 L rows per block -> 16 tiles
#define NT       (LSLICE / 16)        // 16 L-tiles per block
#define UT       16                   // u-tiles per wave (16 MFMA per A-load)
#define BM       1024                 // U rows per kA block (4 waves x 16 x 16)
#define GY       (N_U / BM)           // 4
#define ZREP     2                    // diagnostic duplication (idempotent atomics)
#define LDS_STRIDE 80                 // 64B f16 + 16B pad: bank base lc*20+g*4,
                                      // 5 coprime 32 -> uniform 2 lanes/bank

// workspace layout
#define OFF_P1   0                            // u32 P1key[N_U] (16 KB)
#define OFF_USQ  (16 * 1024)                  // float usq[N_U]  (16 KB)
#define OFF_LF   (32 * 1024)                  // _Float16 Lf16[N_L][32] (4 MB)
#define OFF_LSQ  (OFF_LF + N_L * NZ * 2)      // float lsqh[N_L] = -0.5*||l||^2
#define OFF_UF   (OFF_LSQ + N_L * 4)          // _Float16 Uf16[N_U][32]

// Order-preserving float <-> uint key (monotone for all finite floats)
__device__ __forceinline__ unsigned int f2key(float f) {
    unsigned int u = __float_as_uint(f);
    return (u & 0x80000000u) ? ~u : (u | 0x80000000u);
}
__device__ __forceinline__ float key2f(unsigned int k) {
    unsigned int u = (k & 0x80000000u) ? (k & 0x7FFFFFFFu) : ~k;
    return __uint_as_float(u);
}

// ---------------------------------------------------------------------------
// Precompute: L -> f16 + (-0.5*||l||^2); U -> f16 + ||u||^2; init P1key.
__global__ __launch_bounds__(256) void kPre(const float* __restrict__ Uz,
                                            const float* __restrict__ Lz,
                                            _Float16* __restrict__ Lf16,
                                            float* __restrict__ lsqh,
                                            _Float16* __restrict__ Uf16,
                                            float* __restrict__ usq,
                                            unsigned int* __restrict__ P1key) {
    int r = blockIdx.x * 256 + threadIdx.x;
    if (r < N_L) {
        const f32x4* src = (const f32x4*)(Lz + (size_t)r * NZ);
        _Float16* dst = Lf16 + (size_t)r * NZ;
        float s = 0.f;
#pragma unroll
        for (int j = 0; j < 4; ++j) {
            f32x4 a = src[2 * j], b = src[2 * j + 1];
            s = fmaf(a[0], a[0], s); s = fmaf(a[1], a[1], s);
            s = fmaf(a[2], a[2], s); s = fmaf(a[3], a[3], s);
            s = fmaf(b[0], b[0], s); s = fmaf(b[1], b[1], s);
            s = fmaf(b[2], b[2], s); s = fmaf(b[3], b[3], s);
            *(half8*)(dst + j * 8) =
                (half8){(_Float16)a[0], (_Float16)a[1], (_Float16)a[2], (_Float16)a[3],
                        (_Float16)b[0], (_Float16)b[1], (_Float16)b[2], (_Float16)b[3]};
        }
        lsqh[r] = -0.5f * s;
    } else if (r < N_L + N_U) {
        int u = r - N_L;
        const f32x4* src = (const f32x4*)(Uz + (size_t)u * NZ);
        _Float16* dst = Uf16 + (size_t)u * NZ;
        float s = 0.f;
#pragma unroll
        for (int j = 0; j < 4; ++j) {
            f32x4 a = src[2 * j], b = src[2 * j + 1];
            s = fmaf(a[0], a[0], s); s = fmaf(a[1], a[1], s);
            s = fmaf(a[2], a[2], s); s = fmaf(a[3], a[3], s);
            s = fmaf(b[0], b[0], s); s = fmaf(b[1], b[1], s);
            s = fmaf(b[2], b[2], s); s = fmaf(b[3], b[3], s);
            *(half8*)(dst + j * 8) =
                (half8){(_Float16)a[0], (_Float16)a[1], (_Float16)a[2], (_Float16)a[3],
                        (_Float16)b[0], (_Float16)b[1], (_Float16)b[2], (_Float16)b[3]};
        }
        usq[u] = s;
        P1key[u] = 0u;   // key-space -inf
    }
}

// ---------------------------------------------------------------------------
// Heavy kernel — EXACT R17 structure (LDS-staged L-slice, stride-80,
// UT=16 pinned bfrag, wave stagger, waves_per_eu(4,4), builtin MFMA —
// the builtin is mandatory: raw asm MFMA drops the compiler's MFMA->VALU
// hazard nops and corrupts D reads, R19). ZREP=2 for counter visibility.
__global__ __launch_bounds__(256)
__attribute__((amdgpu_waves_per_eu(4, 4)))
void kA(const _Float16* __restrict__ Lf16,
        const float* __restrict__ lsqh,
        const _Float16* __restrict__ Uf16,
        unsigned int* __restrict__ P1key) {
    __shared__ __align__(16) unsigned char sm[LSLICE * LDS_STRIDE + LSLICE * 4];
    float* slsq = (float*)(sm + LSLICE * LDS_STRIDE);

    const int tid  = threadIdx.x;
    const int lane = tid & 63;
    const int wave = tid >> 6;
    const int g    = lane >> 4;    // k-chunk 0..3 (k = g*8+e, same perm A and B)
    const int lc   = lane & 15;

    const int ubase = blockIdx.y * BM + wave * (UT * 16);
    const int lbase = blockIdx.x * LSLICE;

    // ---- stage: thread t -> L row t (4 x 16B, coalesced global, 2-way LDS)
    {
        const half8* src = (const half8*)(Lf16 + (size_t)(lbase + tid) * NZ);
        unsigned char* dst = sm + tid * LDS_STRIDE;
#pragma unroll
        for (int j = 0; j < 4; ++j)
            *(half8*)(dst + j * 16) = src[j];
        slsq[tid] = lsqh[lbase + tid];
    }

    half8 bfrag[UT];
#pragma unroll
    for (int t = 0; t < UT; ++t)
        bfrag[t] = *(const half8*)(Uf16 + (size_t)(ubase + t * 16 + lc) * NZ + g * 8);
    // Pin B-fragments: opaque non-rematerializable defs (R13: kept resident).
#pragma unroll
    for (int t = 0; t < UT; ++t)
        asm volatile("" : "+v"(bfrag[t]));

    float m[UT];
#pragma unroll
    for (int t = 0; t < UT; ++t) m[t] = -INFINITY;

    __syncthreads();

    const unsigned char* abase = sm + lc * LDS_STRIDE + g * 16;

#pragma unroll 2
    for (int lt = 0; lt < NT; ++lt) {
        const int pt = (lt + wave * 4) & (NT - 1);   // per-wave phase stagger
        half8 a = *(const half8*)(abase + pt * (16 * LDS_STRIDE));
        f32x4 c = *(const f32x4*)(slsq + pt * 16 + g * 4);   // 16-lane broadcast
#pragma unroll
        for (int t = 0; t < UT; ++t) {
            f32x4 x = __builtin_amdgcn_mfma_f32_16x16x32_f16(a, bfrag[t], c, 0, 0, 0);
            float y = fmaxf(fmaxf(x[0], x[1]), x[2]);        // v_max3
            m[t] = fmaxf(fmaxf(y, x[3]), m[t]);              // v_max3
        }
    }

#pragma unroll
    for (int t = 0; t < UT; ++t) {
        float v = m[t];
        v = fmaxf(v, __shfl_xor(v, 16));
        v = fmaxf(v, __shfl_xor(v, 32));
        if (g == 0)
            atomicMax(&P1key[ubase + t * 16 + lc], f2key(v));
    }
}

// ---------------------------------------------------------------------------
// Single-block finisher: dd, global min/max, normalize. Reads 32 KB only.
__global__ __launch_bounds__(1024) void kB(const unsigned int* __restrict__ P1key,
                                           const float* __restrict__ usq,
                                           float* __restrict__ out) {
    const int t    = threadIdx.x;       // 0..1023, each handles 4 u's
    const int lane = t & 63;
    const int wid  = t >> 6;

    u32x4 kv = ((const u32x4*)P1key)[t];
    f32x4 uq = ((const f32x4*)usq)[t];

    float dd[4], lmin = INFINITY, lmax = -INFINITY;
#pragma unroll
    for (int j = 0; j < 4; ++j) {
        float M   = key2f(kv[j]);                       // max(u.l - 0.5||l||^2)
        float sq  = fmaxf(fmaf(-2.f, M, uq[j]), 0.f);   // min squared distance
        float dens = -0.5f * uq[j] - 29.406033062549525f;
        dd[j] = expf(dens) * (sqrtf(sq) + 1e-18f);
        lmin = fminf(lmin, dd[j]);
        lmax = fmaxf(lmax, dd[j]);
    }

    __shared__ float smn[16], smx[16];
#pragma unroll
    for (int o = 1; o < 64; o <<= 1) {
        lmin = fminf(lmin, __shfl_xor(lmin, o));
        lmax = fmaxf(lmax, __shfl_xor(lmax, o));
    }
    if (lane == 0) { smn[wid] = lmin; smx[wid] = lmax; }
    __syncthreads();
    if (wid == 0) {
        float a = (lane < 16) ? smn[lane] : INFINITY;
        float b = (lane < 16) ? smx[lane] : -INFINITY;
#pragma unroll
        for (int o = 1; o < 16; o <<= 1) {
            a = fminf(a, __shfl_xor(a, o));
            b = fmaxf(b, __shfl_xor(b, o));
        }
        if (lane == 0) { smn[0] = a; smx[0] = b; }
    }
    __syncthreads();
    float mn = smn[0], mx = smx[0];
    float inv = 1.f / ((mx - mn) + 1e-18f);

    f32x4 o4 = (f32x4){(dd[0] - mn) * inv, (dd[1] - mn) * inv,
                       (dd[2] - mn) * inv, (dd[3] - mn) * inv};
    ((f32x4*)out)[t] = o4;
}

// ---------------------------------------------------------------------------
extern "C" void kernel_launch(void* const* d_in, const int* in_sizes, int n_in,
                              void* d_out, int out_size, void* d_ws, size_t ws_size,
                              hipStream_t stream) {
    const float* Uz = (const float*)d_in[1];
    const float* Lz = (const float*)d_in[2];
    float* out = (float*)d_out;
    unsigned char* ws = (unsigned char*)d_ws;

    unsigned int* P1key = (unsigned int*)(ws + OFF_P1);
    float*        usq   = (float*)(ws + OFF_USQ);
    _Float16*     Lf16  = (_Float16*)(ws + OFF_LF);
    float*        lsqh  = (float*)(ws + OFF_LSQ);
    _Float16*     Uf16  = (_Float16*)(ws + OFF_UF);

    kPre<<<(N_L + N_U + 255) / 256, 256, 0, stream>>>(Uz, Lz, Lf16, lsqh, Uf16, usq, P1key);
    dim3 grid(NSPLIT, GY, ZREP);   // z=2: diagnostic duplication -> kA counters
    kA<<<grid, 256, 0, stream>>>(Lf16, lsqh, Uf16, P1key);
    kB<<<1, 1024, 0, stream>>>(P1key, usq, out);
}

// Round 21
// 35.047 us; speedup vs baseline: 2.4071x; 1.4552x over previous
//
#include <hip/hip_runtime.h>
#include <hip/hip_bf16.h>

typedef _Float16 half8 __attribute__((ext_vector_type(8)));
typedef float f32x4 __attribute__((ext_vector_type(4)));
typedef unsigned int u32x4 __attribute__((ext_vector_type(4)));

#define N_U      4096
#define N_L      65536
#define NZ       32
#define NSPLIT   256                  // L splits (grid.x of kA)
#define LSLICE   (N_L / NSPLIT)       // 256 L rows per block -> 16 tiles
#define NT       (LSLICE / 16)        // 16 L-tiles per block
#define UT       16                   // u-tiles per wave (16 MFMA per A-load)
#define BM       1024                 // U rows per kA block (4 waves x 16 x 16)
#define GY       (N_U / BM)           // 4

// workspace layout
#define OFF_P1   0                            // u32 P1key[N_U] (16 KB)
#define OFF_USQ  (16 * 1024)                  // float usq[N_U]  (16 KB)
#define OFF_LF   (32 * 1024)                  // _Float16 Lf16[N_L][32] (4 MB)
#define OFF_LSQ  (OFF_LF + N_L * NZ * 2)      // float lsqh[N_L] = -0.5*||l||^2
#define OFF_UF   (OFF_LSQ + N_L * 4)          // _Float16 Uf16[N_U][32]

// Order-preserving float <-> uint key (monotone for all finite floats)
__device__ __forceinline__ unsigned int f2key(float f) {
    unsigned int u = __float_as_uint(f);
    return (u & 0x80000000u) ? ~u : (u | 0x80000000u);
}
__device__ __forceinline__ float key2f(unsigned int k) {
    unsigned int u = (k & 0x80000000u) ? (k & 0x7FFFFFFFu) : ~k;
    return __uint_as_float(u);
}

// ---------------------------------------------------------------------------
// Precompute: L -> f16 + (-0.5*||l||^2); U -> f16 + ||u||^2; init P1key.
__global__ __launch_bounds__(256) void kPre(const float* __restrict__ Uz,
                                            const float* __restrict__ Lz,
                                            _Float16* __restrict__ Lf16,
                                            float* __restrict__ lsqh,
                                            _Float16* __restrict__ Uf16,
                                            float* __restrict__ usq,
                                            unsigned int* __restrict__ P1key) {
    int r = blockIdx.x * 256 + threadIdx.x;
    if (r < N_L) {
        const f32x4* src = (const f32x4*)(Lz + (size_t)r * NZ);
        _Float16* dst = Lf16 + (size_t)r * NZ;
        float s = 0.f;
#pragma unroll
        for (int j = 0; j < 4; ++j) {
            f32x4 a = src[2 * j], b = src[2 * j + 1];
            s = fmaf(a[0], a[0], s); s = fmaf(a[1], a[1], s);
            s = fmaf(a[2], a[2], s); s = fmaf(a[3], a[3], s);
            s = fmaf(b[0], b[0], s); s = fmaf(b[1], b[1], s);
            s = fmaf(b[2], b[2], s); s = fmaf(b[3], b[3], s);
            *(half8*)(dst + j * 8) =
                (half8){(_Float16)a[0], (_Float16)a[1], (_Float16)a[2], (_Float16)a[3],
                        (_Float16)b[0], (_Float16)b[1], (_Float16)b[2], (_Float16)b[3]};
        }
        lsqh[r] = -0.5f * s;
    } else if (r < N_L + N_U) {
        int u = r - N_L;
        const f32x4* src = (const f32x4*)(Uz + (size_t)u * NZ);
        _Float16* dst = Uf16 + (size_t)u * NZ;
        float s = 0.f;
#pragma unroll
        for (int j = 0; j < 4; ++j) {
            f32x4 a = src[2 * j], b = src[2 * j + 1];
            s = fmaf(a[0], a[0], s); s = fmaf(a[1], a[1], s);
            s = fmaf(a[2], a[2], s); s = fmaf(a[3], a[3], s);
            s = fmaf(b[0], b[0], s); s = fmaf(b[1], b[1], s);
            s = fmaf(b[2], b[2], s); s = fmaf(b[3], b[3], s);
            *(half8*)(dst + j * 8) =
                (half8){(_Float16)a[0], (_Float16)a[1], (_Float16)a[2], (_Float16)a[3],
                        (_Float16)b[0], (_Float16)b[1], (_Float16)b[2], (_Float16)b[3]};
        }
        usq[u] = s;
        P1key[u] = 0u;   // key-space -inf
    }
}

// ---------------------------------------------------------------------------
// Heavy kernel (R17 structure). Two fixes from R20's counters:
// 1) LANE-LINEAR LDS layout: row r chunk j stored at (r>>4)*1024+j*256+
//    (r&15)*16, so a wave's A-read is sm + pt*1024 + lane*16 = contiguous
//    1KB -> canonical conflict-free (R20: stride-80 had 8-way aliasing,
//    524288 conflict cycles/dispatch).
// 2) Pin MFMA result x to arch VGPRs ("+v" after the BUILTIN — builtin stays
//    visible so backend hazard nops remain, unlike R19's fatal raw-asm):
//    R20 showed D in AGPRs -> 64 v_accvgpr_read/iter/wave (VALU 266 vs 80
//    source cyc) and 152 regs/wave -> 3 waves/SIMD.
__global__ __launch_bounds__(256)
__attribute__((amdgpu_waves_per_eu(4, 4)))
void kA(const _Float16* __restrict__ Lf16,
        const float* __restrict__ lsqh,
        const _Float16* __restrict__ Uf16,
        unsigned int* __restrict__ P1key) {
    __shared__ __align__(16) unsigned char sm[LSLICE * 64 + LSLICE * 4];
    float* slsq = (float*)(sm + LSLICE * 64);

    const int tid  = threadIdx.x;
    const int lane = tid & 63;
    const int wave = tid >> 6;
    const int g    = lane >> 4;    // k-chunk 0..3 (k = g*8+e, same perm A and B)
    const int lc   = lane & 15;

    const int ubase = blockIdx.y * BM + wave * (UT * 16);
    const int lbase = blockIdx.x * LSLICE;

    // ---- stage: thread t -> L row t, fragment-major (lane-linear reads)
    {
        const half8* src = (const half8*)(Lf16 + (size_t)(lbase + tid) * NZ);
        unsigned char* dst = sm + ((tid >> 4) * 1024) + ((tid & 15) * 16);
#pragma unroll
        for (int j = 0; j < 4; ++j)
            *(half8*)(dst + j * 256) = src[j];
        slsq[tid] = lsqh[lbase + tid];
    }

    half8 bfrag[UT];
#pragma unroll
    for (int t = 0; t < UT; ++t)
        bfrag[t] = *(const half8*)(Uf16 + (size_t)(ubase + t * 16 + lc) * NZ + g * 8);
    // Pin B-fragments: opaque non-rematerializable defs.
#pragma unroll
    for (int t = 0; t < UT; ++t)
        asm volatile("" : "+v"(bfrag[t]));

    float m[UT];
#pragma unroll
    for (int t = 0; t < UT; ++t) m[t] = -INFINITY;

    __syncthreads();

    const unsigned char* abase = sm + lane * 16;

#pragma unroll 2
    for (int lt = 0; lt < NT; ++lt) {
        const int pt = (lt + wave * 4) & (NT - 1);   // per-wave phase stagger
        half8 a = *(const half8*)(abase + pt * 1024);    // contiguous 1KB/wave
        f32x4 c = *(const f32x4*)(slsq + pt * 16 + g * 4);   // 16-lane broadcast
#pragma unroll
        for (int t = 0; t < UT; ++t) {
            f32x4 x = __builtin_amdgcn_mfma_f32_16x16x32_f16(a, bfrag[t], c, 0, 0, 0);
            asm volatile("" : "+v"(x));   // D in arch VGPRs: no accvgpr churn
            float y = fmaxf(fmaxf(x[0], x[1]), x[2]);        // v_max3
            m[t] = fmaxf(fmaxf(y, x[3]), m[t]);              // v_max3
        }
    }

#pragma unroll
    for (int t = 0; t < UT; ++t) {
        float v = m[t];
        v = fmaxf(v, __shfl_xor(v, 16));
        v = fmaxf(v, __shfl_xor(v, 32));
        if (g == 0)
            atomicMax(&P1key[ubase + t * 16 + lc], f2key(v));
    }
}

// ---------------------------------------------------------------------------
// Single-block finisher: dd, global min/max, normalize. Reads 32 KB only.
__global__ __launch_bounds__(1024) void kB(const unsigned int* __restrict__ P1key,
                                           const float* __restrict__ usq,
                                           float* __restrict__ out) {
    const int t    = threadIdx.x;       // 0..1023, each handles 4 u's
    const int lane = t & 63;
    const int wid  = t >> 6;

    u32x4 kv = ((const u32x4*)P1key)[t];
    f32x4 uq = ((const f32x4*)usq)[t];

    float dd[4], lmin = INFINITY, lmax = -INFINITY;
#pragma unroll
    for (int j = 0; j < 4; ++j) {
        float M   = key2f(kv[j]);                       // max(u.l - 0.5||l||^2)
        float sq  = fmaxf(fmaf(-2.f, M, uq[j]), 0.f);   // min squared distance
        float dens = -0.5f * uq[j] - 29.406033062549525f;
        dd[j] = expf(dens) * (sqrtf(sq) + 1e-18f);
        lmin = fminf(lmin, dd[j]);
        lmax = fmaxf(lmax, dd[j]);
    }

    __shared__ float smn[16], smx[16];
#pragma unroll
    for (int o = 1; o < 64; o <<= 1) {
        lmin = fminf(lmin, __shfl_xor(lmin, o));
        lmax = fmaxf(lmax, __shfl_xor(lmax, o));
    }
    if (lane == 0) { smn[wid] = lmin; smx[wid] = lmax; }
    __syncthreads();
    if (wid == 0) {
        float a = (lane < 16) ? smn[lane] : INFINITY;
        float b = (lane < 16) ? smx[lane] : -INFINITY;
#pragma unroll
        for (int o = 1; o < 16; o <<= 1) {
            a = fminf(a, __shfl_xor(a, o));
            b = fmaxf(b, __shfl_xor(b, o));
        }
        if (lane == 0) { smn[0] = a; smx[0] = b; }
    }
    __syncthreads();
    float mn = smn[0], mx = smx[0];
    float inv = 1.f / ((mx - mn) + 1e-18f);

    f32x4 o4 = (f32x4){(dd[0] - mn) * inv, (dd[1] - mn) * inv,
                       (dd[2] - mn) * inv, (dd[3] - mn) * inv};
    ((f32x4*)out)[t] = o4;
}

// ---------------------------------------------------------------------------
extern "C" void kernel_launch(void* const* d_in, const int* in_sizes, int n_in,
                              void* d_out, int out_size, void* d_ws, size_t ws_size,
                              hipStream_t stream) {
    const float* Uz = (const float*)d_in[1];
    const float* Lz = (const float*)d_in[2];
    float* out = (float*)d_out;
    unsigned char* ws = (unsigned char*)d_ws;

    unsigned int* P1key = (unsigned int*)(ws + OFF_P1);
    float*        usq   = (float*)(ws + OFF_USQ);
    _Float16*     Lf16  = (_Float16*)(ws + OFF_LF);
    float*        lsqh  = (float*)(ws + OFF_LSQ);
    _Float16*     Uf16  = (_Float16*)(ws + OFF_UF);

    kPre<<<(N_L + N_U + 255) / 256, 256, 0, stream>>>(Uz, Lz, Lf16, lsqh, Uf16, usq, P1key);
    dim3 grid(NSPLIT, GY);   // 256 x 4 = 1024 blocks
    kA<<<grid, 256, 0, stream>>>(Lf16, lsqh, Uf16, P1key);
    kB<<<1, 1024, 0, stream>>>(P1key, usq, out);
}